// Round 1
// 897.185 us; speedup vs baseline: 1.0434x; 1.0434x over previous
//
#include <hip/hip_runtime.h>
#include <hip/hip_bf16.h>

typedef unsigned short u16;
typedef __bf16 bf16x8 __attribute__((ext_vector_type(8)));
typedef float f32x4 __attribute__((ext_vector_type(4)));

static __device__ __forceinline__ float b2f(u16 x) {
    unsigned int u = ((unsigned int)x) << 16;
    float f; __builtin_memcpy(&f, &u, 4); return f;
}
static __device__ __forceinline__ float b2f_u32(unsigned int u) {
    float f; __builtin_memcpy(&f, &u, 4); return f;
}
static __device__ __forceinline__ u16 f2b(float f) {
    unsigned int u; __builtin_memcpy(&u, &f, 4);
    unsigned int lsb = (u >> 16) & 1u;
    u += 0x7fffu + lsb;
    return (u16)(u >> 16);
}

// async 16B global->LDS (wave-uniform LDS base + lane*16)
static __device__ __forceinline__ void gload16(const u16* g, u16* l) {
    __builtin_amdgcn_global_load_lds(
        (const __attribute__((address_space(1))) unsigned int*)g,
        (__attribute__((address_space(3))) unsigned int*)l, 16, 0, 0);
}

// ---------------- transpose+convert: src fp32 [R][C] -> dst bf16 [C][R] ----------------
__global__ __launch_bounds__(256) void transpose_f2b(const float* __restrict__ src,
                                                     u16* __restrict__ dst,
                                                     int R, int C) {
    __shared__ u16 tile[32][33];
    int c0 = blockIdx.x * 32, r0 = blockIdx.y * 32;
    int tx = threadIdx.x & 31, ty = threadIdx.x >> 5;
    for (int i = ty; i < 32; i += 8) {
        int r = r0 + i, c = c0 + tx;
        tile[i][tx] = (r < R && c < C) ? f2b(src[(long)r * C + c]) : (u16)0;
    }
    __syncthreads();
    for (int i = ty; i < 32; i += 8) {
        int c = c0 + i, r = r0 + tx;
        if (c < C && r < R) dst[(long)c * R + r] = tile[tx][i];
    }
}

// ---------------- concat 3 fp32 bias vectors of 1024 ----------------
__global__ __launch_bounds__(256) void concat3(const float* a, const float* b, const float* c,
                                               float* out) {
    int i = blockIdx.x * 256 + threadIdx.x;
    if (i < 1024) out[i] = a[i];
    else if (i < 2048) out[i] = b[i - 1024];
    else if (i < 3072) out[i] = c[i - 2048];
}

// ---------------- fp32 -> bf16 bulk convert ----------------
__global__ __launch_bounds__(256) void conv_f2b(const float* __restrict__ src,
                                                u16* __restrict__ dst, long n) {
    long i = ((long)blockIdx.x * 256 + threadIdx.x) * 4;
    if (i >= n) return;
    float4 f = *(const float4*)(src + i);
    ushort4 o;
    o.x = f2b(f.x); o.y = f2b(f.y); o.z = f2b(f.z); o.w = f2b(f.w);
    *(ushort4*)(dst + i) = o;
}

// ---------------- m97-style bt-GEMM (all dims multiples of 128/BK) ----------------
// C[M][N] = A[M][K] * B[N][K]^T + bias[N], optional relu. A,B,C bf16, bias fp32.
#define BM 128
#define BN 128
#define BK 32
__global__ __launch_bounds__(256) void gemm_bt(
    const u16* __restrict__ A, const u16* __restrict__ B,
    const float* __restrict__ bias, u16* __restrict__ C,
    int M, int N, int K, int lda, int ldb, int ldc, int relu) {
    __shared__ __align__(16) u16 As[BM][BK];
    __shared__ __align__(16) u16 Bs[BN][BK];

    int m0 = blockIdx.y * BM;
    int n0 = blockIdx.x * BN;
    int tid = threadIdx.x;
    int lane = tid & 63;
    int wave = tid >> 6;
    int wm = (wave >> 1) * 64;
    int wn = (wave & 1) * 64;
    int lrow = lane & 15;
    int quad = lane >> 4;

    f32x4 acc[4][4];
#pragma unroll
    for (int i = 0; i < 4; i++)
#pragma unroll
        for (int j = 0; j < 4; j++) acc[i][j] = (f32x4){0.f, 0.f, 0.f, 0.f};

    const u16* Arow = A + (long)m0 * lda;
    const u16* Brow = B + (long)n0 * ldb;

    for (int k0 = 0; k0 < K; k0 += BK) {
#pragma unroll
        for (int i = 0; i < 2; i++) {
            int idx = (i * 4 + wave) * 64 + lane;
            int row = idx >> 2;
            int seg = (idx & 3) * 8;
            gload16(Arow + (long)row * lda + k0 + seg, &As[0][0] + (i * 4 + wave) * 512);
            gload16(Brow + (long)row * ldb + k0 + seg, &Bs[0][0] + (i * 4 + wave) * 512);
        }
        __syncthreads();

        bf16x8 af[4], bfr[4];
#pragma unroll
        for (int mi = 0; mi < 4; mi++)
            af[mi] = *(const bf16x8*)&As[wm + mi * 16 + lrow][quad * 8];
#pragma unroll
        for (int ni = 0; ni < 4; ni++)
            bfr[ni] = *(const bf16x8*)&Bs[wn + ni * 16 + lrow][quad * 8];
#pragma unroll
        for (int mi = 0; mi < 4; mi++)
#pragma unroll
            for (int ni = 0; ni < 4; ni++)
                acc[mi][ni] = __builtin_amdgcn_mfma_f32_16x16x32_bf16(
                    af[mi], bfr[ni], acc[mi][ni], 0, 0, 0);
        __syncthreads();
    }

#pragma unroll
    for (int mi = 0; mi < 4; mi++) {
        int r0w = m0 + wm + mi * 16 + quad * 4;
#pragma unroll
        for (int ni = 0; ni < 4; ni++) {
            int col = n0 + wn + ni * 16 + lrow;
            float bv = bias ? bias[col] : 0.f;
#pragma unroll
            for (int r = 0; r < 4; r++) {
                float v = acc[mi][ni][r] + bv;
                if (relu) v = fmaxf(v, 0.f);
                C[(long)(r0w + r) * ldc + col] = f2b(v);
            }
        }
    }
}

// ---------------- extract v from qkv (bf16), transposed per head ----------------
__global__ __launch_bounds__(256) void split_v(const u16* __restrict__ qkv,
                                               u16* __restrict__ vT) {
    __shared__ u16 tile[32][33];
    int bh = blockIdx.z;
    int b = bh >> 4, h = bh & 15;
    int s0 = blockIdx.x * 32;
    int d0 = blockIdx.y * 32;
    int tx = threadIdx.x & 31, ty = threadIdx.x >> 5;
    for (int i = ty; i < 32; i += 8)
        tile[i][tx] = qkv[((long)(b * 512 + s0 + i)) * 3072 + 2048 + h * 64 + d0 + tx];
    __syncthreads();
    for (int i = ty; i < 32; i += 8)
        vT[((long)bh * 64 + d0 + i) * 512 + s0 + tx] = tile[tx][i];
}

// ---------------- fused attention: scores + mask + softmax + PV ----------------
// grid (2048): flat id decoded XCD-aware so all 8 q-tiles of one bh land on the
// SAME XCD, consecutively -> K/V (128KB per bh) become L2 hits instead of 8x HBM.
// Writes probs fp32 to attnOut[bh][q][k] (bf16-rounded, read back from the s_p
// staging tile with coalesced dwordx4 stores) and ctx bf16 merged-head.
__global__ __launch_bounds__(256) void attn_fused(
    const u16* __restrict__ qkv, const u16* __restrict__ vT,
    const int* __restrict__ mask, float* __restrict__ attnOut,
    u16* __restrict__ ctx) {
    __shared__ __align__(16) u16 s_tile[128][72];     // Q then K-chunk staging
    __shared__ __align__(16) u16 s_p[4][16][136];     // per-wave P chunk (A-layout)
    __shared__ unsigned long long m_bits[8];

    // XCD-aware decode: xcd = id&7 owns bh === xcd (mod 8); within an XCD the
    // 8 mtiles of one bh are consecutive (ids xcd+8t). Bijective on [0,2048).
    int id = blockIdx.x;
    int t_ = id >> 3;
    int mtile = t_ & 7;
    int bh = (id & 7) + ((t_ >> 3) << 3);
    int b = bh >> 4, h = bh & 15;
    int tid = threadIdx.x, lane = tid & 63, wave = tid >> 6;
    int lrow = lane & 15, quad = lane >> 4;
    int m0 = mtile * 64;

    const u16* Qbase = qkv + (long)(b * 512) * 3072 + h * 64;
    const u16* Kbase = Qbase + 1024;

    {   // mask bitmask: bit j of m_bits[c] = (mask[b*512 + c*64 + j] != 0)
        int i0 = wave * 64 + lane;
        unsigned long long bl0 = __ballot(mask[b * 512 + i0] != 0);
        if (lane == 0) m_bits[wave] = bl0;
        unsigned long long bl1 = __ballot(mask[b * 512 + 256 + i0] != 0);
        if (lane == 0) m_bits[4 + wave] = bl1;
    }

    // stage Q tile [64][64]
#pragma unroll
    for (int i = 0; i < 2; i++) {
        int idx = i * 256 + tid;
        int r = idx >> 3, c = (idx & 7) * 8;
        *(uint4*)&s_tile[r][c] = *(const uint4*)(Qbase + (long)(m0 + r) * 3072 + c);
    }
    __syncthreads();
    bf16x8 qf[2];
    qf[0] = *(const bf16x8*)&s_tile[wave * 16 + lrow][0 + quad * 8];
    qf[1] = *(const bf16x8*)&s_tile[wave * 16 + lrow][32 + quad * 8];
    __syncthreads();

    f32x4 sacc[32];
#pragma unroll
    for (int t = 0; t < 32; t++) sacc[t] = (f32x4){0.f, 0.f, 0.f, 0.f};

    // S = Q K^T over 4 chunks of 128 key-rows
    for (int nc = 0; nc < 4; nc++) {
#pragma unroll
        for (int i = 0; i < 4; i++) {
            int idx = i * 256 + tid;
            int r = idx >> 3, c = (idx & 7) * 8;
            *(uint4*)&s_tile[r][c] = *(const uint4*)(Kbase + (long)(nc * 128 + r) * 3072 + c);
        }
        __syncthreads();
#pragma unroll
        for (int ni = 0; ni < 8; ni++) {
            bf16x8 b0 = *(const bf16x8*)&s_tile[ni * 16 + lrow][0 + quad * 8];
            bf16x8 b1 = *(const bf16x8*)&s_tile[ni * 16 + lrow][32 + quad * 8];
            int t = nc * 8 + ni;
            sacc[t] = __builtin_amdgcn_mfma_f32_16x16x32_bf16(qf[0], b0, sacc[t], 0, 0, 0);
            sacc[t] = __builtin_amdgcn_mfma_f32_16x16x32_bf16(qf[1], b1, sacc[t], 0, 0, 0);
        }
        __syncthreads();
    }

    // mask + scale; lane holds rows quad*4+r, cols t*16+lrow
    float mx[4] = {-3.0e38f, -3.0e38f, -3.0e38f, -3.0e38f};
#pragma unroll
    for (int t = 0; t < 32; t++) {
        int col = t * 16 + lrow;
        int on = (int)((m_bits[col >> 6] >> (col & 63)) & 1ull);
#pragma unroll
        for (int r = 0; r < 4; r++) {
            float s = on ? sacc[t][r] * 0.125f : -1e9f;
            sacc[t][r] = s;
            mx[r] = fmaxf(mx[r], s);
        }
    }
#pragma unroll
    for (int off = 1; off < 16; off <<= 1)
#pragma unroll
        for (int r = 0; r < 4; r++) mx[r] = fmaxf(mx[r], __shfl_xor(mx[r], off));
    float sm[4] = {0.f, 0.f, 0.f, 0.f};
#pragma unroll
    for (int t = 0; t < 32; t++)
#pragma unroll
        for (int r = 0; r < 4; r++) {
            float e = __expf(sacc[t][r] - mx[r]);
            sacc[t][r] = e;
            sm[r] += e;
        }
#pragma unroll
    for (int off = 1; off < 16; off <<= 1)
#pragma unroll
        for (int r = 0; r < 4; r++) sm[r] += __shfl_xor(sm[r], off);
#pragma unroll
    for (int r = 0; r < 4; r++) sm[r] = 1.0f / sm[r];
#pragma unroll
    for (int t = 0; t < 32; t++)
#pragma unroll
        for (int r = 0; r < 4; r++) sacc[t][r] *= sm[r];

    // PV: ctx[m][d] = sum_k P[m][k] V^T[d][k]
    // probs are written fp32 (bf16-rounded) from the s_p staging tile with
    // coalesced dwordx4 stores (2 contiguous 512B rows per instruction).
    f32x4 cacc[4];
#pragma unroll
    for (int ni = 0; ni < 4; ni++) cacc[ni] = (f32x4){0.f, 0.f, 0.f, 0.f};
    const u16* vh = vT + (long)bh * 64 * 512;
    int prr = lane >> 5;       // row parity for prob write
    int pcc = lane & 31;       // float4 index within 128-col chunk

    for (int nc = 0; nc < 4; nc++) {
#pragma unroll
        for (int t2 = 0; t2 < 8; t2++) {
            int t = nc * 8 + t2;
#pragma unroll
            for (int r = 0; r < 4; r++)
                s_p[wave][quad * 4 + r][t2 * 16 + lrow] = f2b(sacc[t][r]);
        }
        __syncthreads();

        // coalesced probs write-out of this wave's 16x128 chunk
        {
            float* abase = attnOut + (long)bh * 512 * 512
                         + (long)(m0 + wave * 16) * 512 + nc * 128;
#pragma unroll
            for (int i = 0; i < 8; i++) {
                int row = i * 2 + prr;
                uint2 pv = *(const uint2*)&s_p[wave][row][pcc * 4];
                float4 o;
                o.x = b2f_u32(pv.x << 16);
                o.y = b2f_u32(pv.x & 0xffff0000u);
                o.z = b2f_u32(pv.y << 16);
                o.w = b2f_u32(pv.y & 0xffff0000u);
                *(float4*)(abase + (long)row * 512 + pcc * 4) = o;
            }
        }

#pragma unroll
        for (int kk = 0; kk < 4; kk++) {
            bf16x8 pf = *(const bf16x8*)&s_p[wave][lrow][kk * 32 + quad * 8];
#pragma unroll
            for (int ni = 0; ni < 4; ni++) {
                bf16x8 vf = *(const bf16x8*)(vh + (long)(ni * 16 + lrow) * 512 + nc * 128 + kk * 32 + quad * 8);
                cacc[ni] = __builtin_amdgcn_mfma_f32_16x16x32_bf16(pf, vf, cacc[ni], 0, 0, 0);
            }
        }
    }

    u16* crow = ctx + (long)(b * 512 + m0 + wave * 16 + quad * 4) * 1024 + h * 64 + lrow;
#pragma unroll
    for (int ni = 0; ni < 4; ni++)
#pragma unroll
        for (int r = 0; r < 4; r++) crow[(long)r * 1024 + ni * 16] = f2b(cacc[ni][r]);
}

// ---------------- out = LayerNorm(a + r) * g + beta ----------------
__global__ __launch_bounds__(256) void add_ln(const u16* __restrict__ a,
                                              const void* __restrict__ r, int r_fp32,
                                              const float* __restrict__ g,
                                              const float* __restrict__ beta,
                                              void* __restrict__ out, int out_fp32) {
    long row = blockIdx.x;
    const u16* pa = a + row * 1024;
    int tid = threadIdx.x;
    float v[4];
    float sum = 0.f, sq = 0.f;
#pragma unroll
    for (int j = 0; j < 4; j++) {
        int c = tid + j * 256;
        float rv = r_fp32 ? ((const float*)r)[row * 1024 + c]
                          : b2f(((const u16*)r)[row * 1024 + c]);
        float x = b2f(pa[c]) + rv;
        v[j] = x;
        sum += x;
        sq += x * x;
    }
#pragma unroll
    for (int off = 32; off >= 1; off >>= 1) {
        sum += __shfl_xor(sum, off);
        sq += __shfl_xor(sq, off);
    }
    __shared__ float red[2][4];
    int wave = tid >> 6, lane = tid & 63;
    if (lane == 0) { red[0][wave] = sum; red[1][wave] = sq; }
    __syncthreads();
    sum = red[0][0] + red[0][1] + red[0][2] + red[0][3];
    sq = red[1][0] + red[1][1] + red[1][2] + red[1][3];
    float mu = sum * (1.f / 1024.f);
    float var = sq * (1.f / 1024.f) - mu * mu;
    float rstd = rsqrtf(var + 1e-6f);
#pragma unroll
    for (int j = 0; j < 4; j++) {
        int c = tid + j * 256;
        float y = (v[j] - mu) * rstd * g[c] + beta[c];
        if (out_fp32) ((float*)out)[row * 1024 + c] = y;
        else ((u16*)out)[row * 1024 + c] = f2b(y);
    }
}

extern "C" void kernel_launch(void* const* d_in, const int* in_sizes, int n_in,
                              void* d_out, int out_size, void* d_ws, size_t ws_size,
                              hipStream_t stream) {
    const float* x   = (const float*)d_in[0];
    const float* Wq  = (const float*)d_in[1];
    const float* bq  = (const float*)d_in[2];
    const float* Wk  = (const float*)d_in[3];
    const float* bk  = (const float*)d_in[4];
    const float* Wv  = (const float*)d_in[5];
    const float* bv  = (const float*)d_in[6];
    const float* Wo  = (const float*)d_in[7];
    const float* bo  = (const float*)d_in[8];
    const float* g1  = (const float*)d_in[9];
    const float* be1 = (const float*)d_in[10];
    const float* w1  = (const float*)d_in[11];
    const float* b1  = (const float*)d_in[12];
    const float* w2  = (const float*)d_in[13];
    const float* b2  = (const float*)d_in[14];
    const float* g2  = (const float*)d_in[15];
    const float* be2 = (const float*)d_in[16];
    const int* mask  = (const int*)d_in[17];

    float* out = (float*)d_out;                   // [8192][1024] fp32
    float* attn = out + (long)8192 * 1024;        // [256][512][512] fp32

    char* w = (char*)d_ws;
    auto alloc = [&](size_t bytes) {
        char* p = w;
        w += (bytes + 255) & ~(size_t)255;
        return p;
    };
    u16* WqkvT = (u16*)alloc(3072L * 1024 * 2);
    u16* WoT   = (u16*)alloc(1024L * 1024 * 2);
    u16* w1T   = (u16*)alloc(4096L * 1024 * 2);
    u16* w2T   = (u16*)alloc(1024L * 4096 * 2);
    float* bqkv = (float*)alloc(3072L * 4);
    u16* xb    = (u16*)alloc(8192L * 1024 * 2);
    char* P1 = alloc(8192L * 4096 * 2);  // qkv (48MB) -> ff (64MB)
    u16* qkv = (u16*)P1;
    u16* ff  = (u16*)P1;
    char* P2 = alloc(256L * 64 * 512 * 2);  // vT -> y2
    u16* vT = (u16*)P2;
    u16* y2 = (u16*)P2;
    u16* ctx = (u16*)alloc(8192L * 1024 * 2);
    u16* x1  = (u16*)alloc(8192L * 1024 * 2);
    u16* y   = (u16*)alloc(8192L * 1024 * 2);

    dim3 blk(256);

    transpose_f2b<<<dim3(32, 32), blk, 0, stream>>>(Wq, WqkvT, 1024, 1024);
    transpose_f2b<<<dim3(32, 32), blk, 0, stream>>>(Wk, WqkvT + 1024L * 1024, 1024, 1024);
    transpose_f2b<<<dim3(32, 32), blk, 0, stream>>>(Wv, WqkvT + 2048L * 1024, 1024, 1024);
    transpose_f2b<<<dim3(32, 32), blk, 0, stream>>>(Wo, WoT, 1024, 1024);
    transpose_f2b<<<dim3(128, 32), blk, 0, stream>>>(w1, w1T, 1024, 4096);
    transpose_f2b<<<dim3(32, 128), blk, 0, stream>>>(w2, w2T, 4096, 1024);
    concat3<<<12, blk, 0, stream>>>(bq, bk, bv, bqkv);
    conv_f2b<<<8192, blk, 0, stream>>>(x, xb, 8192L * 1024);

    // qkv = xb @ [Wq|Wk|Wv]^T + bqkv   (M=8192, N=3072, K=1024)
    gemm_bt<<<dim3(24, 64), blk, 0, stream>>>(
        xb, WqkvT, bqkv, qkv, 8192, 3072, 1024, 1024, 1024, 3072, 0);

    split_v<<<dim3(16, 2, 256), blk, 0, stream>>>(qkv, vT);

    // fused attention: probs -> attn (fp32), ctx (bf16 merged heads)
    attn_fused<<<dim3(2048), blk, 0, stream>>>(qkv, vT, mask, attn, ctx);

    // y = ctx @ Wo^T + bo
    gemm_bt<<<dim3(8, 64), blk, 0, stream>>>(
        ctx, WoT, bo, y, 8192, 1024, 1024, 1024, 1024, 1024, 0);

    // x1 = LN(y + x)
    add_ln<<<8192, blk, 0, stream>>>(y, x, 1, g1, be1, x1, 0);

    // ff = relu(x1 @ w1^T + b1)
    gemm_bt<<<dim3(32, 64), blk, 0, stream>>>(
        x1, w1T, b1, ff, 8192, 4096, 1024, 1024, 1024, 4096, 1);

    // y2 = ff @ w2^T + b2
    gemm_bt<<<dim3(8, 64), blk, 0, stream>>>(
        ff, w2T, b2, y2, 8192, 1024, 4096, 4096, 4096, 1024, 0);

    // out = LN(y2 + x1)
    add_ln<<<8192, blk, 0, stream>>>(y2, x1, 0, g2, be2, out, 1);
}

// Round 2
// 864.149 us; speedup vs baseline: 1.0833x; 1.0382x over previous
//
#include <hip/hip_runtime.h>
#include <hip/hip_bf16.h>

typedef unsigned short u16;
typedef __bf16 bf16x8 __attribute__((ext_vector_type(8)));
typedef float f32x4 __attribute__((ext_vector_type(4)));

static __device__ __forceinline__ float b2f(u16 x) {
    unsigned int u = ((unsigned int)x) << 16;
    float f; __builtin_memcpy(&f, &u, 4); return f;
}
static __device__ __forceinline__ float b2f_u32(unsigned int u) {
    float f; __builtin_memcpy(&f, &u, 4); return f;
}
static __device__ __forceinline__ u16 f2b(float f) {
    unsigned int u; __builtin_memcpy(&u, &f, 4);
    unsigned int lsb = (u >> 16) & 1u;
    u += 0x7fffu + lsb;
    return (u16)(u >> 16);
}

// async 16B global->LDS (wave-uniform LDS base + lane*16)
static __device__ __forceinline__ void gload16(const u16* g, u16* l) {
    __builtin_amdgcn_global_load_lds(
        (const __attribute__((address_space(1))) unsigned int*)g,
        (__attribute__((address_space(3))) unsigned int*)l, 16, 0, 0);
}

// ---------------- transpose+convert: src fp32 [R][C] -> dst bf16 [C][R] ----------------
__global__ __launch_bounds__(256) void transpose_f2b(const float* __restrict__ src,
                                                     u16* __restrict__ dst,
                                                     int R, int C) {
    __shared__ u16 tile[32][33];
    int c0 = blockIdx.x * 32, r0 = blockIdx.y * 32;
    int tx = threadIdx.x & 31, ty = threadIdx.x >> 5;
    for (int i = ty; i < 32; i += 8) {
        int r = r0 + i, c = c0 + tx;
        tile[i][tx] = (r < R && c < C) ? f2b(src[(long)r * C + c]) : (u16)0;
    }
    __syncthreads();
    for (int i = ty; i < 32; i += 8) {
        int c = c0 + i, r = r0 + tx;
        if (c < C && r < R) dst[(long)c * R + r] = tile[tx][i];
    }
}

// ---------------- concat 3 fp32 bias vectors of 1024 ----------------
__global__ __launch_bounds__(256) void concat3(const float* a, const float* b, const float* c,
                                               float* out) {
    int i = blockIdx.x * 256 + threadIdx.x;
    if (i < 1024) out[i] = a[i];
    else if (i < 2048) out[i] = b[i - 1024];
    else if (i < 3072) out[i] = c[i - 2048];
}

// ---------------- fp32 -> bf16 bulk convert ----------------
__global__ __launch_bounds__(256) void conv_f2b(const float* __restrict__ src,
                                                u16* __restrict__ dst, long n) {
    long i = ((long)blockIdx.x * 256 + threadIdx.x) * 4;
    if (i >= n) return;
    float4 f = *(const float4*)(src + i);
    ushort4 o;
    o.x = f2b(f.x); o.y = f2b(f.y); o.z = f2b(f.z); o.w = f2b(f.w);
    *(ushort4*)(dst + i) = o;
}

// ---------------- m97-style bt-GEMM 128x128 (kept for N=1024 shapes) ----------------
#define BM 128
#define BN 128
#define BK 32
__global__ __launch_bounds__(256) void gemm_bt(
    const u16* __restrict__ A, const u16* __restrict__ B,
    const float* __restrict__ bias, u16* __restrict__ C,
    int M, int N, int K, int lda, int ldb, int ldc, int relu) {
    __shared__ __align__(16) u16 As[BM][BK];
    __shared__ __align__(16) u16 Bs[BN][BK];

    int m0 = blockIdx.y * BM;
    int n0 = blockIdx.x * BN;
    int tid = threadIdx.x;
    int lane = tid & 63;
    int wave = tid >> 6;
    int wm = (wave >> 1) * 64;
    int wn = (wave & 1) * 64;
    int lrow = lane & 15;
    int quad = lane >> 4;

    f32x4 acc[4][4];
#pragma unroll
    for (int i = 0; i < 4; i++)
#pragma unroll
        for (int j = 0; j < 4; j++) acc[i][j] = (f32x4){0.f, 0.f, 0.f, 0.f};

    const u16* Arow = A + (long)m0 * lda;
    const u16* Brow = B + (long)n0 * ldb;

    for (int k0 = 0; k0 < K; k0 += BK) {
#pragma unroll
        for (int i = 0; i < 2; i++) {
            int idx = (i * 4 + wave) * 64 + lane;
            int row = idx >> 2;
            int seg = (idx & 3) * 8;
            gload16(Arow + (long)row * lda + k0 + seg, &As[0][0] + (i * 4 + wave) * 512);
            gload16(Brow + (long)row * ldb + k0 + seg, &Bs[0][0] + (i * 4 + wave) * 512);
        }
        __syncthreads();

        bf16x8 af[4], bfr[4];
#pragma unroll
        for (int mi = 0; mi < 4; mi++)
            af[mi] = *(const bf16x8*)&As[wm + mi * 16 + lrow][quad * 8];
#pragma unroll
        for (int ni = 0; ni < 4; ni++)
            bfr[ni] = *(const bf16x8*)&Bs[wn + ni * 16 + lrow][quad * 8];
#pragma unroll
        for (int mi = 0; mi < 4; mi++)
#pragma unroll
            for (int ni = 0; ni < 4; ni++)
                acc[mi][ni] = __builtin_amdgcn_mfma_f32_16x16x32_bf16(
                    af[mi], bfr[ni], acc[mi][ni], 0, 0, 0);
        __syncthreads();
    }

#pragma unroll
    for (int mi = 0; mi < 4; mi++) {
        int r0w = m0 + wm + mi * 16 + quad * 4;
#pragma unroll
        for (int ni = 0; ni < 4; ni++) {
            int col = n0 + wn + ni * 16 + lrow;
            float bv = bias ? bias[col] : 0.f;
#pragma unroll
            for (int r = 0; r < 4; r++) {
                float v = acc[mi][ni][r] + bv;
                if (relu) v = fmaxf(v, 0.f);
                C[(long)(r0w + r) * ldc + col] = f2b(v);
            }
        }
    }
}

// ---------------- 256x256 8-phase bt-GEMM (T2 swizzle + T3/T4 counted vmcnt + T5) ----
// C[M][N] = A[M][K] * B[N][K]^T + bias, optional relu. 512 threads = 8 waves (2Mx4N).
// K-tile = 64. LDS: 2 buf x 4 half-tiles (A0,A1,B0,B1) x 16KB = 128 KiB.
// st_16x32 swizzle: logical byte P within a 16KB half-tile (subtiled
// [rowblk][colgrp][16][64B]) is stored at S = P ^ (((P>>9)&1)<<5).
// global_load_lds writes linearly -> global SOURCE is pre-permuted per lane;
// ds_read applies the same XOR. Waves own interleaved 16-row/16-col slabs so
// quadrant (qm,qn) of every wave depends only on half-tiles {A qm, B qn}.
// Schedule per K-tile T (stages tile T+1): issue order A0,B0,A1,B1; quadrant
// order (0,0),(1,0),(1,1),(0,1); waits vmcnt(6) at phases 1-3 (3 half-tiles in
// flight), none at 4; epilogue tile drains 4->2->0.
__global__ __launch_bounds__(512, 1) void gemm_bt256(
    const u16* __restrict__ A, const u16* __restrict__ B,
    const float* __restrict__ bias, u16* __restrict__ C,
    int M, int N, int K, int lda, int ldb, int ldc, int relu, int nbx) {
    __shared__ __align__(16) u16 lds[2][4][8192];

    int nwg = gridDim.x;
    int id = blockIdx.x;
    int swz = (id & 7) * (nwg >> 3) + (id >> 3);   // nwg % 8 == 0 at all call sites
    int bx = swz % nbx, by = swz / nbx;
    long m0 = (long)by * 256, n0 = (long)bx * 256;

    int tid = threadIdx.x, lane = tid & 63, wave = tid >> 6;
    int lrow = lane & 15, quad = lane >> 4;
    int wm2 = wave >> 2;        // M-half of wave (interleaved 16-row slabs)
    int wn2 = wave & 3;         // N-group of wave (interleaved 16-col slabs)

    // swizzled per-lane ds_read base within a 1KB subtile
    int laneRd = (lrow * 64 + quad * 16) ^ (((lrow >> 3) & 1) << 5);
    // stage source coords: lane's 16B slot within its subtile, unswizzled
    int Sl = (lane * 16) ^ (((lane >> 5) & 1) << 5);
    int wr = (Sl >> 6) & 15;    // row within subtile
    int wb = Sl & 63;           // byte within 128B row (16-aligned)

    f32x4 acc[8][4];
#pragma unroll
    for (int i = 0; i < 8; i++)
#pragma unroll
        for (int j = 0; j < 4; j++) acc[i][j] = (f32x4){0.f, 0.f, 0.f, 0.f};
    bf16x8 af[4][2], bfr[2][2];

#define STAGE_HT(nb, ht, kt) do {                                              \
    const char* _gb = ((ht) < 2)                                               \
        ? (const char*)(A + (m0 + (ht) * 128) * lda)                           \
        : (const char*)(B + (n0 + ((ht) - 2) * 128) * ldb);                    \
    long _ld = (long)(((ht) < 2) ? lda : ldb) * 2;                             \
    _Pragma("unroll")                                                          \
    for (int j = 0; j < 2; j++) {                                              \
        int sub = j * 8 + wave;                                                \
        int srow = (sub >> 1) * 16 + wr;                                       \
        int scolb = (sub & 1) * 64 + wb;                                       \
        gload16((const u16*)(_gb + (long)srow * _ld + (long)(kt) * 128 + scolb),\
                &lds[nb][ht][sub << 9]);                                       \
    }                                                                          \
} while (0)

#define DSLOAD_A(qm) do {                                                      \
    const char* _p = _ab + ((qm) << 14);                                       \
    _Pragma("unroll") for (int mi = 0; mi < 4; mi++)                           \
    _Pragma("unroll") for (int kk = 0; kk < 2; kk++)                           \
        af[mi][kk] = *(const bf16x8*)(_p + ((mi * 4 + kk) << 10));             \
} while (0)

#define DSLOAD_B(qn) do {                                                      \
    const char* _p = _bb + ((qn) << 14);                                       \
    _Pragma("unroll") for (int ni = 0; ni < 2; ni++)                           \
    _Pragma("unroll") for (int kk = 0; kk < 2; kk++)                           \
        bfr[ni][kk] = *(const bf16x8*)(_p + ((ni * 8 + kk) << 10));            \
} while (0)

#define DOMFMA(qm, qn) do {                                                    \
    __builtin_amdgcn_s_setprio(1);                                             \
    _Pragma("unroll") for (int mi = 0; mi < 4; mi++)                           \
    _Pragma("unroll") for (int ni = 0; ni < 2; ni++)                           \
    _Pragma("unroll") for (int kk = 0; kk < 2; kk++)                           \
        acc[(qm) * 4 + mi][(qn) * 2 + ni] =                                    \
            __builtin_amdgcn_mfma_f32_16x16x32_bf16(                           \
                af[mi][kk], bfr[ni][kk], acc[(qm) * 4 + mi][(qn) * 2 + ni],    \
                0, 0, 0);                                                      \
    __builtin_amdgcn_s_setprio(0);                                             \
} while (0)

#define MIDBAR()  do { __builtin_amdgcn_s_barrier(); __builtin_amdgcn_sched_barrier(0); } while (0)
#define ENDBAR()  do { __builtin_amdgcn_sched_barrier(0); __builtin_amdgcn_s_barrier(); } while (0)

    int NT = K >> 6;
    // prologue: tile 0 into buf0, issue order A0,B0,A1,B1
    STAGE_HT(0, 0, 0);
    STAGE_HT(0, 2, 0);
    STAGE_HT(0, 1, 0);
    STAGE_HT(0, 3, 0);

    for (int t = 0; t < NT - 1; t++) {
        int cur = t & 1, nxt = cur ^ 1;
        const char* _ab = (const char*)&lds[cur][0][0] + (wm2 << 11) + laneRd;
        const char* _bb = (const char*)&lds[cur][2][0] + (wn2 << 11) + laneRd;
        // P1: quadrant (0,0); stage T+1.A0
        STAGE_HT(nxt, 0, t + 1);
        asm volatile("s_waitcnt vmcnt(6)" ::: "memory");
        MIDBAR();
        DSLOAD_A(0); DSLOAD_B(0); DOMFMA(0, 0);
        ENDBAR();
        // P2: quadrant (1,0); stage T+1.B0
        STAGE_HT(nxt, 2, t + 1);
        asm volatile("s_waitcnt vmcnt(6)" ::: "memory");
        MIDBAR();
        DSLOAD_A(1); DOMFMA(1, 0);
        ENDBAR();
        // P3: quadrant (1,1); stage T+1.A1
        STAGE_HT(nxt, 1, t + 1);
        asm volatile("s_waitcnt vmcnt(6)" ::: "memory");
        MIDBAR();
        DSLOAD_B(1); DOMFMA(1, 1);
        ENDBAR();
        // P4: quadrant (0,1); stage T+1.B1 (no wait: A0,B1 already guaranteed)
        STAGE_HT(nxt, 3, t + 1);
        MIDBAR();
        DSLOAD_A(0); DOMFMA(0, 1);
        ENDBAR();
    }
    {   // tail tile NT-1: no stages; drain 4 -> 2 -> 0
        int cur = (NT - 1) & 1;
        const char* _ab = (const char*)&lds[cur][0][0] + (wm2 << 11) + laneRd;
        const char* _bb = (const char*)&lds[cur][2][0] + (wn2 << 11) + laneRd;
        asm volatile("s_waitcnt vmcnt(4)" ::: "memory");
        MIDBAR();
        DSLOAD_A(0); DSLOAD_B(0); DOMFMA(0, 0);
        ENDBAR();
        asm volatile("s_waitcnt vmcnt(2)" ::: "memory");
        MIDBAR();
        DSLOAD_A(1); DOMFMA(1, 0);
        ENDBAR();
        asm volatile("s_waitcnt vmcnt(0)" ::: "memory");
        MIDBAR();
        DSLOAD_B(1); DOMFMA(1, 1);
        ENDBAR();
        DSLOAD_A(0); DOMFMA(0, 1);
    }

    // epilogue: C-write. row frag = qm*8 + mi*2 + wm2, col frag = qn*8 + ni*4 + wn2
#pragma unroll
    for (int mg = 0; mg < 8; mg++) {
        long row0 = m0 + (long)(((mg >> 2) * 8 + (mg & 3) * 2 + wm2) * 16 + quad * 4);
#pragma unroll
        for (int ng = 0; ng < 4; ng++) {
            long col = n0 + ((ng >> 1) * 8 + (ng & 1) * 4 + wn2) * 16 + lrow;
            float bv = bias ? bias[col] : 0.f;
#pragma unroll
            for (int r = 0; r < 4; r++) {
                float v = acc[mg][ng][r] + bv;
                if (relu) v = fmaxf(v, 0.f);
                C[(row0 + r) * ldc + col] = f2b(v);
            }
        }
    }
#undef STAGE_HT
#undef DSLOAD_A
#undef DSLOAD_B
#undef DOMFMA
#undef MIDBAR
#undef ENDBAR
}

// ---------------- extract v from qkv (bf16), transposed per head ----------------
__global__ __launch_bounds__(256) void split_v(const u16* __restrict__ qkv,
                                               u16* __restrict__ vT) {
    __shared__ u16 tile[32][33];
    int bh = blockIdx.z;
    int b = bh >> 4, h = bh & 15;
    int s0 = blockIdx.x * 32;
    int d0 = blockIdx.y * 32;
    int tx = threadIdx.x & 31, ty = threadIdx.x >> 5;
    for (int i = ty; i < 32; i += 8)
        tile[i][tx] = qkv[((long)(b * 512 + s0 + i)) * 3072 + 2048 + h * 64 + d0 + tx];
    __syncthreads();
    for (int i = ty; i < 32; i += 8)
        vT[((long)bh * 64 + d0 + i) * 512 + s0 + tx] = tile[tx][i];
}

// ---------------- fused attention: scores + mask + softmax + PV ----------------
__global__ __launch_bounds__(256) void attn_fused(
    const u16* __restrict__ qkv, const u16* __restrict__ vT,
    const int* __restrict__ mask, float* __restrict__ attnOut,
    u16* __restrict__ ctx) {
    __shared__ __align__(16) u16 s_tile[128][72];     // Q then K-chunk staging
    __shared__ __align__(16) u16 s_p[4][16][136];     // per-wave P chunk (A-layout)
    __shared__ unsigned long long m_bits[8];

    // XCD-aware decode: xcd = id&7 owns bh === xcd (mod 8); within an XCD the
    // 8 mtiles of one bh are consecutive (ids xcd+8t). Bijective on [0,2048).
    int id = blockIdx.x;
    int t_ = id >> 3;
    int mtile = t_ & 7;
    int bh = (id & 7) + ((t_ >> 3) << 3);
    int b = bh >> 4, h = bh & 15;
    int tid = threadIdx.x, lane = tid & 63, wave = tid >> 6;
    int lrow = lane & 15, quad = lane >> 4;
    int m0 = mtile * 64;

    const u16* Qbase = qkv + (long)(b * 512) * 3072 + h * 64;
    const u16* Kbase = Qbase + 1024;

    {   // mask bitmask: bit j of m_bits[c] = (mask[b*512 + c*64 + j] != 0)
        int i0 = wave * 64 + lane;
        unsigned long long bl0 = __ballot(mask[b * 512 + i0] != 0);
        if (lane == 0) m_bits[wave] = bl0;
        unsigned long long bl1 = __ballot(mask[b * 512 + 256 + i0] != 0);
        if (lane == 0) m_bits[4 + wave] = bl1;
    }

    // stage Q tile [64][64]
#pragma unroll
    for (int i = 0; i < 2; i++) {
        int idx = i * 256 + tid;
        int r = idx >> 3, c = (idx & 7) * 8;
        *(uint4*)&s_tile[r][c] = *(const uint4*)(Qbase + (long)(m0 + r) * 3072 + c);
    }
    __syncthreads();
    bf16x8 qf[2];
    qf[0] = *(const bf16x8*)&s_tile[wave * 16 + lrow][0 + quad * 8];
    qf[1] = *(const bf16x8*)&s_tile[wave * 16 + lrow][32 + quad * 8];
    __syncthreads();

    f32x4 sacc[32];
#pragma unroll
    for (int t = 0; t < 32; t++) sacc[t] = (f32x4){0.f, 0.f, 0.f, 0.f};

    // S = Q K^T over 4 chunks of 128 key-rows
    for (int nc = 0; nc < 4; nc++) {
#pragma unroll
        for (int i = 0; i < 4; i++) {
            int idx = i * 256 + tid;
            int r = idx >> 3, c = (idx & 7) * 8;
            *(uint4*)&s_tile[r][c] = *(const uint4*)(Kbase + (long)(nc * 128 + r) * 3072 + c);
        }
        __syncthreads();
#pragma unroll
        for (int ni = 0; ni < 8; ni++) {
            bf16x8 b0 = *(const bf16x8*)&s_tile[ni * 16 + lrow][0 + quad * 8];
            bf16x8 b1 = *(const bf16x8*)&s_tile[ni * 16 + lrow][32 + quad * 8];
            int t = nc * 8 + ni;
            sacc[t] = __builtin_amdgcn_mfma_f32_16x16x32_bf16(qf[0], b0, sacc[t], 0, 0, 0);
            sacc[t] = __builtin_amdgcn_mfma_f32_16x16x32_bf16(qf[1], b1, sacc[t], 0, 0, 0);
        }
        __syncthreads();
    }

    // mask + scale; lane holds rows quad*4+r, cols t*16+lrow
    float mx[4] = {-3.0e38f, -3.0e38f, -3.0e38f, -3.0e38f};
#pragma unroll
    for (int t = 0; t < 32; t++) {
        int col = t * 16 + lrow;
        int on = (int)((m_bits[col >> 6] >> (col & 63)) & 1ull);
#pragma unroll
        for (int r = 0; r < 4; r++) {
            float s = on ? sacc[t][r] * 0.125f : -1e9f;
            sacc[t][r] = s;
            mx[r] = fmaxf(mx[r], s);
        }
    }
#pragma unroll
    for (int off = 1; off < 16; off <<= 1)
#pragma unroll
        for (int r = 0; r < 4; r++) mx[r] = fmaxf(mx[r], __shfl_xor(mx[r], off));
    float sm[4] = {0.f, 0.f, 0.f, 0.f};
#pragma unroll
    for (int t = 0; t < 32; t++)
#pragma unroll
        for (int r = 0; r < 4; r++) {
            float e = __expf(sacc[t][r] - mx[r]);
            sacc[t][r] = e;
            sm[r] += e;
        }
#pragma unroll
    for (int off = 1; off < 16; off <<= 1)
#pragma unroll
        for (int r = 0; r < 4; r++) sm[r] += __shfl_xor(sm[r], off);
#pragma unroll
    for (int r = 0; r < 4; r++) sm[r] = 1.0f / sm[r];
#pragma unroll
    for (int t = 0; t < 32; t++)
#pragma unroll
        for (int r = 0; r < 4; r++) sacc[t][r] *= sm[r];

    // PV: ctx[m][d] = sum_k P[m][k] V^T[d][k]
    f32x4 cacc[4];
#pragma unroll
    for (int ni = 0; ni < 4; ni++) cacc[ni] = (f32x4){0.f, 0.f, 0.f, 0.f};
    const u16* vh = vT + (long)bh * 64 * 512;
    int prr = lane >> 5;       // row parity for prob write
    int pcc = lane & 31;       // float4 index within 128-col chunk

    for (int nc = 0; nc < 4; nc++) {
#pragma unroll
        for (int t2 = 0; t2 < 8; t2++) {
            int t = nc * 8 + t2;
#pragma unroll
            for (int r = 0; r < 4; r++)
                s_p[wave][quad * 4 + r][t2 * 16 + lrow] = f2b(sacc[t][r]);
        }
        __syncthreads();

        // coalesced probs write-out of this wave's 16x128 chunk
        {
            float* abase = attnOut + (long)bh * 512 * 512
                         + (long)(m0 + wave * 16) * 512 + nc * 128;
#pragma unroll
            for (int i = 0; i < 8; i++) {
                int row = i * 2 + prr;
                uint2 pv = *(const uint2*)&s_p[wave][row][pcc * 4];
                float4 o;
                o.x = b2f_u32(pv.x << 16);
                o.y = b2f_u32(pv.x & 0xffff0000u);
                o.z = b2f_u32(pv.y << 16);
                o.w = b2f_u32(pv.y & 0xffff0000u);
                *(float4*)(abase + (long)row * 512 + pcc * 4) = o;
            }
        }

#pragma unroll
        for (int kk = 0; kk < 4; kk++) {
            bf16x8 pf = *(const bf16x8*)&s_p[wave][lrow][kk * 32 + quad * 8];
#pragma unroll
            for (int ni = 0; ni < 4; ni++) {
                bf16x8 vf = *(const bf16x8*)(vh + (long)(ni * 16 + lrow) * 512 + nc * 128 + kk * 32 + quad * 8);
                cacc[ni] = __builtin_amdgcn_mfma_f32_16x16x32_bf16(pf, vf, cacc[ni], 0, 0, 0);
            }
        }
    }

    u16* crow = ctx + (long)(b * 512 + m0 + wave * 16 + quad * 4) * 1024 + h * 64 + lrow;
#pragma unroll
    for (int ni = 0; ni < 4; ni++)
#pragma unroll
        for (int r = 0; r < 4; r++) crow[(long)r * 1024 + ni * 16] = f2b(cacc[ni][r]);
}

// ---------------- out = LayerNorm(a + r) * g + beta ----------------
__global__ __launch_bounds__(256) void add_ln(const u16* __restrict__ a,
                                              const void* __restrict__ r, int r_fp32,
                                              const float* __restrict__ g,
                                              const float* __restrict__ beta,
                                              void* __restrict__ out, int out_fp32) {
    long row = blockIdx.x;
    const u16* pa = a + row * 1024;
    int tid = threadIdx.x;
    float v[4];
    float sum = 0.f, sq = 0.f;
#pragma unroll
    for (int j = 0; j < 4; j++) {
        int c = tid + j * 256;
        float rv = r_fp32 ? ((const float*)r)[row * 1024 + c]
                          : b2f(((const u16*)r)[row * 1024 + c]);
        float x = b2f(pa[c]) + rv;
        v[j] = x;
        sum += x;
        sq += x * x;
    }
#pragma unroll
    for (int off = 32; off >= 1; off >>= 1) {
        sum += __shfl_xor(sum, off);
        sq += __shfl_xor(sq, off);
    }
    __shared__ float red[2][4];
    int wave = tid >> 6, lane = tid & 63;
    if (lane == 0) { red[0][wave] = sum; red[1][wave] = sq; }
    __syncthreads();
    sum = red[0][0] + red[0][1] + red[0][2] + red[0][3];
    sq = red[1][0] + red[1][1] + red[1][2] + red[1][3];
    float mu = sum * (1.f / 1024.f);
    float var = sq * (1.f / 1024.f) - mu * mu;
    float rstd = rsqrtf(var + 1e-6f);
#pragma unroll
    for (int j = 0; j < 4; j++) {
        int c = tid + j * 256;
        float y = (v[j] - mu) * rstd * g[c] + beta[c];
        if (out_fp32) ((float*)out)[row * 1024 + c] = y;
        else ((u16*)out)[row * 1024 + c] = f2b(y);
    }
}

extern "C" void kernel_launch(void* const* d_in, const int* in_sizes, int n_in,
                              void* d_out, int out_size, void* d_ws, size_t ws_size,
                              hipStream_t stream) {
    const float* x   = (const float*)d_in[0];
    const float* Wq  = (const float*)d_in[1];
    const float* bq  = (const float*)d_in[2];
    const float* Wk  = (const float*)d_in[3];
    const float* bk  = (const float*)d_in[4];
    const float* Wv  = (const float*)d_in[5];
    const float* bv  = (const float*)d_in[6];
    const float* Wo  = (const float*)d_in[7];
    const float* bo  = (const float*)d_in[8];
    const float* g1  = (const float*)d_in[9];
    const float* be1 = (const float*)d_in[10];
    const float* w1  = (const float*)d_in[11];
    const float* b1  = (const float*)d_in[12];
    const float* w2  = (const float*)d_in[13];
    const float* b2  = (const float*)d_in[14];
    const float* g2  = (const float*)d_in[15];
    const float* be2 = (const float*)d_in[16];
    const int* mask  = (const int*)d_in[17];

    float* out = (float*)d_out;                   // [8192][1024] fp32
    float* attn = out + (long)8192 * 1024;        // [256][512][512] fp32

    char* w = (char*)d_ws;
    auto alloc = [&](size_t bytes) {
        char* p = w;
        w += (bytes + 255) & ~(size_t)255;
        return p;
    };
    u16* WqkvT = (u16*)alloc(3072L * 1024 * 2);
    u16* WoT   = (u16*)alloc(1024L * 1024 * 2);
    u16* w1T   = (u16*)alloc(4096L * 1024 * 2);
    u16* w2T   = (u16*)alloc(1024L * 4096 * 2);
    float* bqkv = (float*)alloc(3072L * 4);
    u16* xb    = (u16*)alloc(8192L * 1024 * 2);
    char* P1 = alloc(8192L * 4096 * 2);  // qkv (48MB) -> ff (64MB)
    u16* qkv = (u16*)P1;
    u16* ff  = (u16*)P1;
    char* P2 = alloc(256L * 64 * 512 * 2);  // vT -> y2
    u16* vT = (u16*)P2;
    u16* y2 = (u16*)P2;
    u16* ctx = (u16*)alloc(8192L * 1024 * 2);
    u16* x1  = (u16*)alloc(8192L * 1024 * 2);
    u16* y   = (u16*)alloc(8192L * 1024 * 2);

    dim3 blk(256);

    transpose_f2b<<<dim3(32, 32), blk, 0, stream>>>(Wq, WqkvT, 1024, 1024);
    transpose_f2b<<<dim3(32, 32), blk, 0, stream>>>(Wk, WqkvT + 1024L * 1024, 1024, 1024);
    transpose_f2b<<<dim3(32, 32), blk, 0, stream>>>(Wv, WqkvT + 2048L * 1024, 1024, 1024);
    transpose_f2b<<<dim3(32, 32), blk, 0, stream>>>(Wo, WoT, 1024, 1024);
    transpose_f2b<<<dim3(128, 32), blk, 0, stream>>>(w1, w1T, 1024, 4096);
    transpose_f2b<<<dim3(32, 128), blk, 0, stream>>>(w2, w2T, 4096, 1024);
    concat3<<<12, blk, 0, stream>>>(bq, bk, bv, bqkv);
    conv_f2b<<<8192, blk, 0, stream>>>(x, xb, 8192L * 1024);

    // qkv = xb @ [Wq|Wk|Wv]^T + bqkv   (M=8192, N=3072, K=1024) — 256^2 8-phase
    gemm_bt256<<<dim3(384), dim3(512), 0, stream>>>(
        xb, WqkvT, bqkv, qkv, 8192, 3072, 1024, 1024, 1024, 3072, 0, 12);

    split_v<<<dim3(16, 2, 256), blk, 0, stream>>>(qkv, vT);

    // fused attention: probs -> attn (fp32), ctx (bf16 merged heads)
    attn_fused<<<dim3(2048), blk, 0, stream>>>(qkv, vT, mask, attn, ctx);

    // y = ctx @ Wo^T + bo   (N=1024 -> only 128 tiles of 256^2; keep 128^2 kernel)
    gemm_bt<<<dim3(8, 64), blk, 0, stream>>>(
        ctx, WoT, bo, y, 8192, 1024, 1024, 1024, 1024, 1024, 0);

    // x1 = LN(y + x)
    add_ln<<<8192, blk, 0, stream>>>(y, x, 1, g1, be1, x1, 0);

    // ff = relu(x1 @ w1^T + b1)   (M=8192, N=4096, K=1024) — 256^2 8-phase
    gemm_bt256<<<dim3(512), dim3(512), 0, stream>>>(
        x1, w1T, b1, ff, 8192, 4096, 1024, 1024, 1024, 4096, 1, 16);

    // y2 = ff @ w2^T + b2   (N=1024; keep 128^2 kernel)
    gemm_bt<<<dim3(8, 64), blk, 0, stream>>>(
        ff, w2T, b2, y2, 8192, 1024, 4096, 4096, 4096, 1024, 0);

    // out = LN(y2 + x1)
    add_ln<<<8192, blk, 0, stream>>>(y2, x1, 0, g2, be2, out, 1);
}